// Round 14
// baseline (69.132 us; speedup 1.0000x reference)
//
#include <hip/hip_runtime.h>

typedef float f32x2 __attribute__((ext_vector_type(2)));
typedef float f32x4 __attribute__((ext_vector_type(4)));
typedef short short8 __attribute__((ext_vector_type(8)));  // 8 x bf16 bits
typedef unsigned short ushort4v __attribute__((ext_vector_type(4)));

static __device__ __forceinline__ unsigned short f2bf(float f) {
    __bf16 h = (__bf16)f;
    return __builtin_bit_cast(unsigned short, h);
}

// ---------------------------------------------------------------------------
// Kernel A: contract TT cores into dense TRANSPOSED bf16 weights (as r9).
// ---------------------------------------------------------------------------
__global__ __launch_bounds__(256) void tt_build_w_kernel(
    const float* __restrict__ d1, const float* __restrict__ d2, const float* __restrict__ d3,
    const float* __restrict__ u1, const float* __restrict__ u2, const float* __restrict__ u3,
    unsigned short* __restrict__ WdT, unsigned short* __restrict__ WuT)
{
    int t = blockIdx.x * 256 + threadIdx.x;
    if (t < 65536) {
        int j = t >> 10, i = t & 1023;
        int i1 = i >> 7, i2 = (i >> 3) & 15, i3 = i & 7;
        int j1 = j >> 4, j2 = (j >> 2) & 3, j3 = j & 3;
        float t3[8];
#pragma unroll
        for (int b = 0; b < 8; ++b) t3[b] = d3[(b * 8 + i3) * 4 + j3];
        float wsum = 0.f;
#pragma unroll
        for (int a = 0; a < 8; ++a) {
            float va = d1[(i1 * 4 + j1) * 8 + a];
            const float* p2 = d2 + ((a * 16 + i2) * 4 + j2) * 8;
            float wa = 0.f;
#pragma unroll
            for (int b = 0; b < 8; ++b) wa = fmaf(p2[b], t3[b], wa);
            wsum = fmaf(va, wa, wsum);
        }
        int g = i & 31;
        int h = g >> 4, kgg = (g >> 2) & 3, e = g & 3;
        int pos = (i & ~31) | (kgg * 8 + h * 4 + e);
        WdT[j * 1024 + pos] = f2bf(wsum);
    } else {
        int t2 = t - 65536;
        int d = t2 >> 6, k = t2 & 63;
        int k1 = k >> 4, k2 = (k >> 2) & 3, k3 = k & 3;
        int o1 = d >> 7, o2 = (d >> 3) & 15, o3 = d & 7;
        float t3[8];
#pragma unroll
        for (int b = 0; b < 8; ++b) t3[b] = u3[(b * 4 + k3) * 8 + o3];
        float wsum = 0.f;
#pragma unroll
        for (int a = 0; a < 8; ++a) {
            float va = u1[(k1 * 8 + o1) * 8 + a];
            const float* p2 = u2 + ((a * 4 + k2) * 16 + o2) * 8;
            float wa = 0.f;
#pragma unroll
            for (int b = 0; b < 8; ++b) wa = fmaf(p2[b], t3[b], wa);
            wsum = fmaf(va, wa, wsum);
        }
        WuT[d * 64 + k] = f2bf(wsum);
    }
}

// ---------------------------------------------------------------------------
// PROBE: pure streaming x -> bf16 copy at max occupancy (no LDS, tiny VGPR,
// grid-stride, 2048x256 = 32 waves/CU, the m13-copy regime). Measures the
// achievable read+write stream rate on THIS buffer; Delta-dur vs r9 (50.9us)
// isolates it. Output xbf is an artifact for future rounds (unused now).
// 16.78M floats: thread handles 8 f32x4 groups (4.19M groups / 524288 thr).
// ---------------------------------------------------------------------------
__global__ __launch_bounds__(256) void tt_xcvt_kernel(
    const float* __restrict__ x, unsigned short* __restrict__ xbf)
{
    const int tid = blockIdx.x * 256 + threadIdx.x;   // 0..524287
#pragma unroll
    for (int i = 0; i < 8; ++i) {
        const int g = tid + i * 524288;               // f32x4 group index
        f32x4 v = *reinterpret_cast<const f32x4*>(x + (size_t)g * 4);
        ushort4v o;
        o[0] = f2bf(v[0]); o[1] = f2bf(v[1]); o[2] = f2bf(v[2]); o[3] = f2bf(v[3]);
        *reinterpret_cast<ushort4v*>(xbf + (size_t)g * 4) = o;
    }
}

// asm burst: 16 pinned global_load_dwordx4, dense 64B sectors per row
#define XBURST(dst, ptr)                                                                     \
    do {                                                                                     \
        asm volatile("global_load_dwordx4 %0, %1, off offset:0"   : "=v"(dst[0])  : "v"(ptr) : "memory"); \
        asm volatile("global_load_dwordx4 %0, %1, off offset:64"  : "=v"(dst[1])  : "v"(ptr) : "memory"); \
        asm volatile("global_load_dwordx4 %0, %1, off offset:128" : "=v"(dst[2])  : "v"(ptr) : "memory"); \
        asm volatile("global_load_dwordx4 %0, %1, off offset:192" : "=v"(dst[3])  : "v"(ptr) : "memory"); \
        asm volatile("global_load_dwordx4 %0, %1, off offset:256" : "=v"(dst[4])  : "v"(ptr) : "memory"); \
        asm volatile("global_load_dwordx4 %0, %1, off offset:320" : "=v"(dst[5])  : "v"(ptr) : "memory"); \
        asm volatile("global_load_dwordx4 %0, %1, off offset:384" : "=v"(dst[6])  : "v"(ptr) : "memory"); \
        asm volatile("global_load_dwordx4 %0, %1, off offset:448" : "=v"(dst[7])  : "v"(ptr) : "memory"); \
        asm volatile("global_load_dwordx4 %0, %1, off offset:512" : "=v"(dst[8])  : "v"(ptr) : "memory"); \
        asm volatile("global_load_dwordx4 %0, %1, off offset:576" : "=v"(dst[9])  : "v"(ptr) : "memory"); \
        asm volatile("global_load_dwordx4 %0, %1, off offset:640" : "=v"(dst[10]) : "v"(ptr) : "memory"); \
        asm volatile("global_load_dwordx4 %0, %1, off offset:704" : "=v"(dst[11]) : "v"(ptr) : "memory"); \
        asm volatile("global_load_dwordx4 %0, %1, off offset:768" : "=v"(dst[12]) : "v"(ptr) : "memory"); \
        asm volatile("global_load_dwordx4 %0, %1, off offset:832" : "=v"(dst[13]) : "v"(ptr) : "memory"); \
        asm volatile("global_load_dwordx4 %0, %1, off offset:896" : "=v"(dst[14]) : "v"(ptr) : "memory"); \
        asm volatile("global_load_dwordx4 %0, %1, off offset:960" : "=v"(dst[15]) : "v"(ptr) : "memory"); \
    } while (0)

static __device__ __forceinline__ void mfma_ktile(
    const f32x4 (&xs)[16], const unsigned short* __restrict__ wp, f32x4 (&acc)[4])
{
#pragma unroll
    for (int ks = 0; ks < 8; ++ks) {
        short8 b0 = *reinterpret_cast<const short8*>(wp + 0 * 16384 + ks * 32);
        short8 b1 = *reinterpret_cast<const short8*>(wp + 1 * 16384 + ks * 32);
        short8 b2 = *reinterpret_cast<const short8*>(wp + 2 * 16384 + ks * 32);
        short8 b3 = *reinterpret_cast<const short8*>(wp + 3 * 16384 + ks * 32);
        union { short8 v; unsigned short e[8]; } a;
        a.e[0] = f2bf(xs[2 * ks][0]); a.e[1] = f2bf(xs[2 * ks][1]);
        a.e[2] = f2bf(xs[2 * ks][2]); a.e[3] = f2bf(xs[2 * ks][3]);
        a.e[4] = f2bf(xs[2 * ks + 1][0]); a.e[5] = f2bf(xs[2 * ks + 1][1]);
        a.e[6] = f2bf(xs[2 * ks + 1][2]); a.e[7] = f2bf(xs[2 * ks + 1][3]);
        acc[0] = __builtin_amdgcn_mfma_f32_16x16x32_bf16(a.v, b0, acc[0], 0, 0, 0);
        acc[1] = __builtin_amdgcn_mfma_f32_16x16x32_bf16(a.v, b1, acc[1], 0, 0, 0);
        acc[2] = __builtin_amdgcn_mfma_f32_16x16x32_bf16(a.v, b2, acc[2], 0, 0, 0);
        acc[3] = __builtin_amdgcn_mfma_f32_16x16x32_bf16(a.v, b3, acc[3], 0, 0, 0);
    }
}

// ---------------------------------------------------------------------------
// K1: z = relu(x @ Wd + bd) -> zbuf (byte-identical to r9)
// ---------------------------------------------------------------------------
__global__ __launch_bounds__(256, 4) void tt_gemm1_kernel(
    const float* __restrict__ x, const unsigned short* __restrict__ WdT,
    const float* __restrict__ bd, unsigned short* __restrict__ zbuf)
{
    __shared__ float red[4][1024];
    const int t = threadIdx.x;
    const int lane = t & 63;
    const int w = t >> 6;
    const int l15 = lane & 15;
    const int kg = lane >> 4;
    const int kb = w * 256;
    const int tile = blockIdx.x;

    const float* xp = x + (size_t)(tile * 16 + l15) * 1024 + kb + kg * 4;
    f32x4 xs[16];
    XBURST(xs, xp);

    const int colz = (t >> 6) * 16 + (t & 15);
    const int rowz = ((t & 63) >> 4) * 4;
    const float bdv = bd[colz];
    const unsigned short* wp = WdT + l15 * 1024 + kb + kg * 8;

    asm volatile("s_waitcnt vmcnt(0)" ::: "memory");
    __builtin_amdgcn_sched_barrier(0);
    f32x4 acc[4] = {{0.f, 0.f, 0.f, 0.f}, {0.f, 0.f, 0.f, 0.f},
                    {0.f, 0.f, 0.f, 0.f}, {0.f, 0.f, 0.f, 0.f}};
    mfma_ktile(xs, wp, acc);

#pragma unroll
    for (int ct = 0; ct < 4; ++ct)
        *reinterpret_cast<f32x4*>(&red[w][ct * 256 + lane * 4]) = acc[ct];
    __syncthreads();
    {
        f32x4 v0 = *reinterpret_cast<const f32x4*>(&red[0][t * 4]);
        f32x4 v1 = *reinterpret_cast<const f32x4*>(&red[1][t * 4]);
        f32x4 v2 = *reinterpret_cast<const f32x4*>(&red[2][t * 4]);
        f32x4 v3 = *reinterpret_cast<const f32x4*>(&red[3][t * 4]);
#pragma unroll
        for (int r = 0; r < 4; ++r) {
            float zz = v0[r] + v1[r] + v2[r] + v3[r] + bdv;
            zz = zz > 0.f ? zz : 0.f;
            zbuf[tile * 1024 + (rowz + r) * 64 + colz] = f2bf(zz);
        }
    }
}

// ---------------------------------------------------------------------------
// K2: y = z @ Wu + bu (byte-identical to r9)
// ---------------------------------------------------------------------------
__global__ __launch_bounds__(256) void tt_gemm2_kernel(
    const unsigned short* __restrict__ zbuf, const unsigned short* __restrict__ WuT,
    const float* __restrict__ bu, float* __restrict__ y)
{
    __shared__ unsigned short wlds[512 * 64];   // 64 KB
    const int t = threadIdx.x;
    const int lane = t & 63;
    const int w = t >> 6;
    const int l15 = lane & 15;
    const int kg = lane >> 4;
    const int ch = blockIdx.x & 1;
    const int rg = blockIdx.x >> 1;

    const unsigned short* src = WuT + ch * 512 * 64;
#pragma unroll
    for (int i = 0; i < 16; ++i) {
        int idx = i * 256 + t;
        int dst = idx ^ ((idx >> 3) & 7);
        *reinterpret_cast<short8*>(&wlds[dst * 8]) =
            *reinterpret_cast<const short8*>(src + idx * 8);
    }
    f32x4 bv[8];
#pragma unroll
    for (int i = 0; i < 8; ++i)
        bv[i] = *reinterpret_cast<const f32x4*>(bu + ch * 512 + w * 128 + i * 16 + kg * 4);
    __syncthreads();

#pragma unroll
    for (int tt = 0; tt < 4; ++tt) {
        const int tile = rg * 4 + tt;
        short8 az0 = *reinterpret_cast<const short8*>(zbuf + tile * 1024 + l15 * 64 + kg * 8);
        short8 az1 = *reinterpret_cast<const short8*>(zbuf + tile * 1024 + l15 * 64 + 32 + kg * 8);
        const size_t yb = (size_t)(tile * 16 + l15) * 1024 + ch * 512 + w * 128;
#pragma unroll
        for (int i = 0; i < 8; ++i) {
            const int row = w * 128 + i * 16 + l15;
            const int s = row & 7;
            short8 b0 = *reinterpret_cast<const short8*>(&wlds[(row * 8 + (kg ^ s)) * 8]);
            short8 b1 = *reinterpret_cast<const short8*>(&wlds[(row * 8 + ((kg + 4) ^ s)) * 8]);
            f32x4 c = {0.f, 0.f, 0.f, 0.f};
            c = __builtin_amdgcn_mfma_f32_16x16x32_bf16(b0, az0, c, 0, 0, 0);
            c = __builtin_amdgcn_mfma_f32_16x16x32_bf16(b1, az1, c, 0, 0, 0);
            f32x4 o;
#pragma unroll
            for (int r = 0; r < 4; ++r) o[r] = c[r] + bv[i][r];
            *reinterpret_cast<f32x4*>(y + yb + i * 16 + kg * 4) = o;
        }
    }
}

extern "C" void kernel_launch(void* const* d_in, const int* in_sizes, int n_in,
                              void* d_out, int out_size, void* d_ws, size_t ws_size,
                              hipStream_t stream) {
    const float* x  = (const float*)d_in[0];
    const float* d1 = (const float*)d_in[1];
    const float* d2 = (const float*)d_in[2];
    const float* d3 = (const float*)d_in[3];
    const float* u1 = (const float*)d_in[4];
    const float* u2 = (const float*)d_in[5];
    const float* u3 = (const float*)d_in[6];
    const float* bd = (const float*)d_in[7];
    const float* bu = (const float*)d_in[8];
    float* y = (float*)d_out;
    unsigned short* WdT  = (unsigned short*)d_ws;   // 64x1024 bf16 (128 KB)
    unsigned short* WuT  = WdT + 65536;             // 1024x64 bf16 (128 KB)
    unsigned short* zbuf = WuT + 65536;             // 2 MB
    unsigned short* xbf  = zbuf + 1048576;          // 16.78M bf16 (32 MB) probe artifact

    hipLaunchKernelGGL(tt_build_w_kernel, dim3(512), dim3(256), 0, stream,
                       d1, d2, d3, u1, u2, u3, WdT, WuT);
    // PROBE: pure 64MB-read + 32MB-write stream at 32 waves/CU.
    // Delta-dur vs r9 (50.9us) = this kernel's duration.
    hipLaunchKernelGGL(tt_xcvt_kernel, dim3(2048), dim3(256), 0, stream,
                       x, xbf);
    hipLaunchKernelGGL(tt_gemm1_kernel, dim3(1024), dim3(256), 0, stream,
                       x, WdT, bd, zbuf);
    hipLaunchKernelGGL(tt_gemm2_kernel, dim3(512), dim3(256), 0, stream,
                       zbuf, WuT, bu, y);
}

// Round 15
// 36.363 us; speedup vs baseline: 1.9012x; 1.9012x over previous
//
#include <hip/hip_runtime.h>

typedef float f32x2 __attribute__((ext_vector_type(2)));
typedef float f32x4 __attribute__((ext_vector_type(4)));
typedef short short8 __attribute__((ext_vector_type(8)));  // 8 x bf16 bits

static __device__ __forceinline__ unsigned short f2bf(float f) {
    __bf16 h = (__bf16)f;
    return __builtin_bit_cast(unsigned short, h);
}

// async global->LDS, 16B/lane: lane i fetches its own 16B (per-lane source
// address) and HW writes LDS at dest + i*16 (dest must be wave-uniform).
static __device__ __forceinline__ void gload_lds16(const void* g, void* l) {
    __builtin_amdgcn_global_load_lds(
        (const __attribute__((address_space(1))) void*)g,
        (__attribute__((address_space(3))) void*)l, 16, 0, 0);
}

// ---------------------------------------------------------------------------
// Kernel A: contract TT cores into PRE-ARRANGED bf16 weights for LDS staging.
//  WdT_sw: [w 0..3][ck 0..3][(ks2*4+kg)*64 + j][m] with value
//          Wd[k = w*256 + ck*64 + ks2*32 + kg*8 + m][j]
//          -> gemm1 stages chunk (w,ck) = 8KB linearly; B-frag read at
//             granule (ks2*4+kg)*64 + j is bank-spread (j in low bits).
//  WuT_sw: r9's XOR-swizzled layout, pre-applied: granule (d,kgrp) stored at
//          local granule d8*8 + (kgrp ^ (d8&7)) within its 64KB col-half
//          -> gemm2 stages linearly; reads with r9's verified formula.
// ---------------------------------------------------------------------------
__global__ __launch_bounds__(256) void tt_build_w_kernel(
    const float* __restrict__ d1, const float* __restrict__ d2, const float* __restrict__ d3,
    const float* __restrict__ u1, const float* __restrict__ u2, const float* __restrict__ u3,
    unsigned short* __restrict__ WdT_sw, unsigned short* __restrict__ WuT_sw)
{
    int t = blockIdx.x * 256 + threadIdx.x;
    if (t < 65536) {
        int j = t >> 10, i = t & 1023;
        int i1 = i >> 7, i2 = (i >> 3) & 15, i3 = i & 7;
        int j1 = j >> 4, j2 = (j >> 2) & 3, j3 = j & 3;
        float t3[8];
#pragma unroll
        for (int b = 0; b < 8; ++b) t3[b] = d3[(b * 8 + i3) * 4 + j3];
        float wsum = 0.f;
#pragma unroll
        for (int a = 0; a < 8; ++a) {
            float va = d1[(i1 * 4 + j1) * 8 + a];
            const float* p2 = d2 + ((a * 16 + i2) * 4 + j2) * 8;
            float wa = 0.f;
#pragma unroll
            for (int b = 0; b < 8; ++b) wa = fmaf(p2[b], t3[b], wa);
            wsum = fmaf(va, wa, wsum);
        }
        int w_ = i >> 8, ck = (i >> 6) & 3, ks2 = (i >> 5) & 1;
        int kg_ = (i >> 3) & 3, m = i & 7;
        int off = (w_ * 4 + ck) * 4096 + ((ks2 * 4 + kg_) * 64 + j) * 8 + m;
        WdT_sw[off] = f2bf(wsum);
    } else {
        int t2 = t - 65536;
        int d = t2 >> 6, k = t2 & 63;
        int k1 = k >> 4, k2 = (k >> 2) & 3, k3 = k & 3;
        int o1 = d >> 7, o2 = (d >> 3) & 15, o3 = d & 7;
        float t3[8];
#pragma unroll
        for (int b = 0; b < 8; ++b) t3[b] = u3[(b * 4 + k3) * 8 + o3];
        float wsum = 0.f;
#pragma unroll
        for (int a = 0; a < 8; ++a) {
            float va = u1[(k1 * 8 + o1) * 8 + a];
            const float* p2 = u2 + ((a * 4 + k2) * 16 + o2) * 8;
            float wa = 0.f;
#pragma unroll
            for (int b = 0; b < 8; ++b) wa = fmaf(p2[b], t3[b], wa);
            wsum = fmaf(va, wa, wsum);
        }
        int dl = d & 511, hf = d >> 9;
        int off = hf * 32768 + (dl * 8 + ((k >> 3) ^ (dl & 7))) * 8 + (k & 7);
        WuT_sw[off] = f2bf(wsum);
    }
}

// ---------------------------------------------------------------------------
// K1 v2: z = relu(x @ Wd + bd) -> zbuf[tile][m16][j64].
// 512 blocks x 256 thr (4 waves). Block = 2 tiles; wave w owns K-quarter
// [256w,+256) of BOTH tiles (WdT VMEM amortized x2 vs r9: 128->64 MB total).
// Wave-local flow, NO barrier in the K-loop:
//   stage chunks 0,1 (gload_lds, 8KB each) ->
//   4x { 8 pinned x-loads (both tiles); vmcnt(0); ds_read B-frags from own
//        LDS region; 16 MFMA; restage chunk+2 into the freed buffer }
// Weights ride the DS port; VMEM carries only x (HBM) + 32KB/wave staging.
// Then r9's verified reduce (tile0, tile1 sequentially through red).
// ---------------------------------------------------------------------------
__global__ __launch_bounds__(256) void tt_gemm1_kernel(
    const float* __restrict__ x, const unsigned short* __restrict__ WdT_sw,
    const float* __restrict__ bd, unsigned short* __restrict__ zbuf)
{
    __shared__ unsigned short wlds[4][2][4096];  // [wave][buf][8KB] = 64 KB
    __shared__ float red[4][1024];               // 16 KB
    const int t = threadIdx.x;
    const int lane = t & 63;
    const int w = t >> 6;
    const int l15 = lane & 15;
    const int kg = lane >> 4;
    const int tile0 = blockIdx.x * 2;

    const int colz = (t >> 6) * 16 + (t & 15);
    const int rowz = ((t & 63) >> 4) * 4;
    const float bdv = bd[colz];

    const unsigned short* wsrc = WdT_sw + w * 16384 + lane * 8;  // per-lane src
    const float* xp0 = x + (size_t)(tile0 * 16 + l15) * 1024 + w * 256 + kg * 8;
    const float* xp1 = xp0 + 16 * 1024;

    // prologue: stage chunks 0,1
#pragma unroll
    for (int i = 0; i < 8; ++i)
        gload_lds16(wsrc + i * 512, &wlds[w][0][i * 512]);
#pragma unroll
    for (int i = 0; i < 8; ++i)
        gload_lds16(wsrc + 4096 + i * 512, &wlds[w][1][i * 512]);

    f32x4 xs[8];
    f32x4 acc0[4] = {{0.f, 0.f, 0.f, 0.f}, {0.f, 0.f, 0.f, 0.f},
                     {0.f, 0.f, 0.f, 0.f}, {0.f, 0.f, 0.f, 0.f}};
    f32x4 acc1[4] = {{0.f, 0.f, 0.f, 0.f}, {0.f, 0.f, 0.f, 0.f},
                     {0.f, 0.f, 0.f, 0.f}, {0.f, 0.f, 0.f, 0.f}};

#define XL8(o0, o1, o2, o3)                                                                        \
    asm volatile("global_load_dwordx4 %0, %1, off offset:" #o0 : "=v"(xs[0]) : "v"(xp0) : "memory"); \
    asm volatile("global_load_dwordx4 %0, %1, off offset:" #o1 : "=v"(xs[1]) : "v"(xp0) : "memory"); \
    asm volatile("global_load_dwordx4 %0, %1, off offset:" #o2 : "=v"(xs[2]) : "v"(xp0) : "memory"); \
    asm volatile("global_load_dwordx4 %0, %1, off offset:" #o3 : "=v"(xs[3]) : "v"(xp0) : "memory"); \
    asm volatile("global_load_dwordx4 %0, %1, off offset:" #o0 : "=v"(xs[4]) : "v"(xp1) : "memory"); \
    asm volatile("global_load_dwordx4 %0, %1, off offset:" #o1 : "=v"(xs[5]) : "v"(xp1) : "memory"); \
    asm volatile("global_load_dwordx4 %0, %1, off offset:" #o2 : "=v"(xs[6]) : "v"(xp1) : "memory"); \
    asm volatile("global_load_dwordx4 %0, %1, off offset:" #o3 : "=v"(xs[7]) : "v"(xp1) : "memory");

    // COMPUTE for chunk in buffer BUF: 8 ds_reads + 16 MFMA (2 tiles x 2 ks2 x 4 ct)
#define CPT(BUF) do {                                                                       \
    asm volatile("s_waitcnt vmcnt(0)" ::: "memory");                                        \
    __builtin_amdgcn_sched_barrier(0);                                                      \
    const unsigned short* lb = &wlds[w][BUF][0];                                            \
    _Pragma("unroll")                                                                       \
    for (int ks2 = 0; ks2 < 2; ++ks2) {                                                     \
        union { short8 v; unsigned short e[8]; } a0, a1;                                    \
        _Pragma("unroll")                                                                   \
        for (int e = 0; e < 4; ++e) {                                                       \
            a0.e[e] = f2bf(xs[ks2 * 2][e]);     a0.e[e + 4] = f2bf(xs[ks2 * 2 + 1][e]);     \
            a1.e[e] = f2bf(xs[4 + ks2 * 2][e]); a1.e[e + 4] = f2bf(xs[4 + ks2 * 2 + 1][e]); \
        }                                                                                   \
        _Pragma("unroll")                                                                   \
        for (int ct = 0; ct < 4; ++ct) {                                                    \
            short8 bf = *reinterpret_cast<const short8*>(                                   \
                lb + (ks2 * 4 + kg) * 512 + ct * 128 + l15 * 8);                            \
            acc0[ct] = __builtin_amdgcn_mfma_f32_16x16x32_bf16(a0.v, bf, acc0[ct], 0, 0, 0); \
            acc1[ct] = __builtin_amdgcn_mfma_f32_16x16x32_bf16(a1.v, bf, acc1[ct], 0, 0, 0); \
        }                                                                                   \
    }                                                                                       \
    __builtin_amdgcn_sched_barrier(0);                                                      \
} while (0)

    // ck=0
    XL8(0, 16, 128, 144)
    CPT(0);
#pragma unroll
    for (int i = 0; i < 8; ++i)          // restage: chunk 2 -> buf0
        gload_lds16(wsrc + 2 * 4096 + i * 512, &wlds[w][0][i * 512]);
    // ck=1
    XL8(256, 272, 384, 400)
    CPT(1);
#pragma unroll
    for (int i = 0; i < 8; ++i)          // restage: chunk 3 -> buf1
        gload_lds16(wsrc + 3 * 4096 + i * 512, &wlds[w][1][i * 512]);
    // ck=2
    XL8(512, 528, 640, 656)
    CPT(0);
    // ck=3
    XL8(768, 784, 896, 912)
    CPT(1);
#undef XL8
#undef CPT

    // -------- reduce tile0 then tile1 through red (r9-verified pattern) ----
#pragma unroll
    for (int ct = 0; ct < 4; ++ct)
        *reinterpret_cast<f32x4*>(&red[w][ct * 256 + lane * 4]) = acc0[ct];
    __syncthreads();
    {
        f32x4 v0 = *reinterpret_cast<const f32x4*>(&red[0][t * 4]);
        f32x4 v1 = *reinterpret_cast<const f32x4*>(&red[1][t * 4]);
        f32x4 v2 = *reinterpret_cast<const f32x4*>(&red[2][t * 4]);
        f32x4 v3 = *reinterpret_cast<const f32x4*>(&red[3][t * 4]);
#pragma unroll
        for (int r = 0; r < 4; ++r) {
            float zz = v0[r] + v1[r] + v2[r] + v3[r] + bdv;
            zz = zz > 0.f ? zz : 0.f;
            zbuf[tile0 * 1024 + (rowz + r) * 64 + colz] = f2bf(zz);
        }
    }
    __syncthreads();
#pragma unroll
    for (int ct = 0; ct < 4; ++ct)
        *reinterpret_cast<f32x4*>(&red[w][ct * 256 + lane * 4]) = acc1[ct];
    __syncthreads();
    {
        f32x4 v0 = *reinterpret_cast<const f32x4*>(&red[0][t * 4]);
        f32x4 v1 = *reinterpret_cast<const f32x4*>(&red[1][t * 4]);
        f32x4 v2 = *reinterpret_cast<const f32x4*>(&red[2][t * 4]);
        f32x4 v3 = *reinterpret_cast<const f32x4*>(&red[3][t * 4]);
#pragma unroll
        for (int r = 0; r < 4; ++r) {
            float zz = v0[r] + v1[r] + v2[r] + v3[r] + bdv;
            zz = zz > 0.f ? zz : 0.f;
            zbuf[(tile0 + 1) * 1024 + (rowz + r) * 64 + colz] = f2bf(zz);
        }
    }
}

// ---------------------------------------------------------------------------
// K2 v2: y = z @ Wu + bu. 256 blocks x 256 thr (4 waves); block = 8 tiles x
// col-half (staging VMEM halved vs r9: 32->16 MB, amortized x8). WuT-half
// (64 KB) staged via gload_lds from the PRE-swizzled WuT_sw -> read formulas
// are byte-identical to r9's verified ones. One barrier; then pure stream:
// per tile {2 z loads, 8x(2 LDS b128 + 2 MFMA + bias)} -> dwordx4 stores.
// ---------------------------------------------------------------------------
__global__ __launch_bounds__(256) void tt_gemm2_kernel(
    const unsigned short* __restrict__ zbuf, const unsigned short* __restrict__ WuT_sw,
    const float* __restrict__ bu, float* __restrict__ y)
{
    __shared__ unsigned short wlds[32768];   // 64 KB
    const int t = threadIdx.x;
    const int lane = t & 63;
    const int w = t >> 6;
    const int l15 = lane & 15;
    const int kg = lane >> 4;
    const int ch = blockIdx.x & 1;
    const int rg = blockIdx.x >> 1;          // 0..127

    // stage WuT half: wave w covers 16 KB linearly
    const unsigned short* src = WuT_sw + ch * 32768 + w * 8192 + lane * 8;
#pragma unroll
    for (int i = 0; i < 16; ++i)
        gload_lds16(src + i * 512, &wlds[w * 8192 + i * 512]);

    f32x4 bv[8];
#pragma unroll
    for (int i = 0; i < 8; ++i)
        bv[i] = *reinterpret_cast<const f32x4*>(bu + ch * 512 + w * 128 + i * 16 + kg * 4);
    __syncthreads();

#pragma unroll
    for (int tt = 0; tt < 8; ++tt) {
        const int tile = rg * 8 + tt;
        short8 az0 = *reinterpret_cast<const short8*>(zbuf + tile * 1024 + l15 * 64 + kg * 8);
        short8 az1 = *reinterpret_cast<const short8*>(zbuf + tile * 1024 + l15 * 64 + 32 + kg * 8);
        const size_t yb = (size_t)(tile * 16 + l15) * 1024 + ch * 512 + w * 128;
#pragma unroll
        for (int i = 0; i < 8; ++i) {
            const int row = w * 128 + i * 16 + l15;
            const int s = row & 7;
            short8 b0 = *reinterpret_cast<const short8*>(&wlds[(row * 8 + (kg ^ s)) * 8]);
            short8 b1 = *reinterpret_cast<const short8*>(&wlds[(row * 8 + ((kg + 4) ^ s)) * 8]);
            f32x4 c = {0.f, 0.f, 0.f, 0.f};
            c = __builtin_amdgcn_mfma_f32_16x16x32_bf16(b0, az0, c, 0, 0, 0);
            c = __builtin_amdgcn_mfma_f32_16x16x32_bf16(b1, az1, c, 0, 0, 0);
            f32x4 o;
#pragma unroll
            for (int r = 0; r < 4; ++r) o[r] = c[r] + bv[i][r];
            *reinterpret_cast<f32x4*>(y + yb + i * 16 + kg * 4) = o;
        }
    }
}

extern "C" void kernel_launch(void* const* d_in, const int* in_sizes, int n_in,
                              void* d_out, int out_size, void* d_ws, size_t ws_size,
                              hipStream_t stream) {
    const float* x  = (const float*)d_in[0];
    const float* d1 = (const float*)d_in[1];
    const float* d2 = (const float*)d_in[2];
    const float* d3 = (const float*)d_in[3];
    const float* u1 = (const float*)d_in[4];
    const float* u2 = (const float*)d_in[5];
    const float* u3 = (const float*)d_in[6];
    const float* bd = (const float*)d_in[7];
    const float* bu = (const float*)d_in[8];
    float* y = (float*)d_out;
    unsigned short* WdT_sw = (unsigned short*)d_ws;   // 128 KB, staged layout
    unsigned short* WuT_sw = WdT_sw + 65536;          // 128 KB, pre-swizzled
    unsigned short* zbuf   = WuT_sw + 65536;          // 2 MB

    hipLaunchKernelGGL(tt_build_w_kernel, dim3(512), dim3(256), 0, stream,
                       d1, d2, d3, u1, u2, u3, WdT_sw, WuT_sw);
    hipLaunchKernelGGL(tt_gemm1_kernel, dim3(512), dim3(256), 0, stream,
                       x, WdT_sw, bd, zbuf);
    hipLaunchKernelGGL(tt_gemm2_kernel, dim3(256), dim3(256), 0, stream,
                       zbuf, WuT_sw, bu, y);
}